// Round 16
// baseline (825.347 us; speedup 1.0000x reference)
//
#include <hip/hip_runtime.h>

// Problem constants (from reference)
#define KA 240000
#define NI 4
#define MG 50
#define NSEL 256u
#define CAPL 4096          // boundary-bin member cap per group (expect ~260)
#define BPI 235            // blocks per image: 235*256*4 = 240640 >= 240000
#define GRID (BPI * NI)    // 940 blocks <= co-resident capacity (1024 at 4 blk/CU)

typedef unsigned int u32;

// ws layout (u32 units):
//   hist : [0, 16384)    8 groups x 2048 bins (key>>21)
//   meta : [16384, 16416)  us[8] | R[8] | done[8] | cnt[8]
//   bars : [16416, 16420)  4 grid-barrier counters
//   list : [16420, +8*CAPL*2)  (key, globalIdx) boundary-bin members
//   verd : [after list, +8*CAPL)  per-slot verdict (written for every slot)
#define METAO 16384
#define BARO  (METAO + 32)
#define LISTO (BARO + 4)
#define VERDO (LISTO + 8 * CAPL * 2)

// monotone f32 -> u32 sortkey (order-preserving for all finite floats)
static __device__ __forceinline__ u32 sortkey32(float f) {
    u32 b = __float_as_uint(f);
    return (b & 0x80000000u) ? ~b : (b | 0x80000000u);
}
static __device__ __forceinline__ u32 aload(const u32* p) {
    return __hip_atomic_load(p, __ATOMIC_ACQUIRE, __HIP_MEMORY_SCOPE_AGENT);
}
static __device__ __forceinline__ void astore(u32* p, u32 v) {
    __hip_atomic_store(p, v, __ATOMIC_RELEASE, __HIP_MEMORY_SCOPE_AGENT);
}
// grid barrier: valid because all GRID blocks are co-resident (persistent kernel)
static __device__ __forceinline__ void gbar(u32* bar) {
    __syncthreads();
    if (threadIdx.x == 0) {
        __hip_atomic_fetch_add(bar, 1u, __ATOMIC_ACQ_REL, __HIP_MEMORY_SCOPE_AGENT);
        while (__hip_atomic_load(bar, __ATOMIC_ACQUIRE, __HIP_MEMORY_SCOPE_AGENT) < (u32)GRID)
            __builtin_amdgcn_s_sleep(2);
    }
    __syncthreads();
}

// ---------------- D0: zero hist + meta + barrier counters ----------------
__global__ void __launch_bounds__(256) kZ(u32* __restrict__ ws) {
    for (int i = blockIdx.x * 256 + threadIdx.x; i < LISTO; i += gridDim.x * 256)
        ws[i] = 0;
}

// ---------------- D1: fully fused persistent kernel ----------------
// Inputs are f32 (established R5-R13).
extern "C" __global__ void __launch_bounds__(256, 4)
AnchorTargetLayer_48052094107725_kernel(
    const float4* __restrict__ anchors, const float* __restrict__ scores,
    const float4* __restrict__ gtb, const int* __restrict__ glab,
    float* __restrict__ out, u32* __restrict__ ws) {
#pragma clang fp contract(off)
    __shared__ float4 gA[MG];
    __shared__ int glb[MG];
    __shared__ u32 lh[2048];        // packed hist: pos low16 | neg high16
    __shared__ u32 cs[256];
    __shared__ u32 s_meta[32];
    __shared__ u32 h2[1024];
    __shared__ u32 tk[256], ti[256], tj[256];
    __shared__ u32 s_usb, s_R2, s_tc;

    u32* hist = ws;
    u32* meta = ws + METAO;
    u32* bars = ws + BARO;
    u32* list = ws + LISTO;
    u32* verd = ws + VERDO;

    const int bx = blockIdx.x;
    const int tid = threadIdx.x;
    const int n = bx / BPI;
    const int kb = bx - n * BPI;

    // ---------- P1: exact-f32 IoU/argmax + targets + LDS histogram ----------
    for (int i = tid; i < 2048; i += 256) lh[i] = 0;
    if (tid < MG) {
        gA[tid] = gtb[n * MG + tid];
        glb[tid] = glab[n * MG + tid];
    }
    __syncthreads();

    const int k0 = (kb * 256 + tid) * 4;   // 4 consecutive anchors (KA%4==0)
    const bool act = (k0 < KA);
    u32 keyv[4] = {0, 0, 0, 0};
    u32 flagpack = 0;
    if (act) {
        float ax0[4], ay0[4], ax2[4], ay2[4];
        #pragma unroll
        for (int j = 0; j < 4; ++j) {
            const float4 A = anchors[k0 + j];
            ax0[j] = A.x; ay0[j] = A.y; ax2[j] = A.z; ay2[j] = A.w;
        }
        float aaw[4], aah[4], aar[4], bst[4];
        int bix[4];
        #pragma unroll
        for (int j = 0; j < 4; ++j) {
            aaw[j] = ax2[j] - ax0[j];
            aah[j] = ay2[j] - ay0[j];
            aar[j] = aaw[j] * aah[j];
            bst[j] = -1.0f;
            bix[j] = 0;
        }
        for (int m = 0; m < MG; m += 2) {
            const float4 Ga = gA[m];
            const float4 Gb = gA[m + 1];
            const float gaA = (Ga.z - Ga.x) * (Ga.w - Ga.y);   // same ops as reference
            const float gaB = (Gb.z - Gb.x) * (Gb.w - Gb.y);
            #pragma unroll
            for (int j = 0; j < 4; ++j) {
                const float wa = fmaxf(fminf(ax2[j], Ga.z) - fmaxf(ax0[j], Ga.x), 0.0f);
                const float ha = fmaxf(fminf(ay2[j], Ga.w) - fmaxf(ay0[j], Ga.y), 0.0f);
                const float ia = wa * ha;
                const float qa = ia / (((aar[j] + gaA) - ia) + 1e-8f);  // IEEE f32 div
                const float wb = fmaxf(fminf(ax2[j], Gb.z) - fmaxf(ax0[j], Gb.x), 0.0f);
                const float hb = fmaxf(fminf(ay2[j], Gb.w) - fmaxf(ay0[j], Gb.y), 0.0f);
                const float ib = wb * hb;
                const float qb = ib / (((aar[j] + gaB) - ib) + 1e-8f);
                if (qa > bst[j]) { bst[j] = qa; bix[j] = m; }       // strict >: first idx
                if (qb > bst[j]) { bst[j] = qb; bix[j] = m + 1; }
            }
        }
        const int nk = n * KA + k0;
        const float4 s4 = ((const float4*)scores)[nk >> 2];
        const float scv[4] = {s4.x, s4.y, s4.z, s4.w};
        float clsv[4];
        float4 regv[4];
        #pragma unroll
        for (int j = 0; j < 4; ++j) {
            const bool pos = bst[j] >= 0.7f;
            const bool neg = bst[j] < 0.3f;
            clsv[j] = pos ? (float)glb[bix[j]] : 0.0f;
            float4 rv = make_float4(0.0f, 0.0f, 0.0f, 0.0f);
            if (pos) {
                const float4 Gm = gA[bix[j]];
                const float gw = Gm.z - Gm.x, gh = Gm.w - Gm.y;
                const float gcx = Gm.x + 0.5f * gw, gcy = Gm.y + 0.5f * gh;
                const float acx = ax0[j] + 0.5f * aaw[j], acy = ay0[j] + 0.5f * aah[j];
                rv.x = (gcx - acx) / aaw[j];
                rv.y = (gcy - acy) / aah[j];
                rv.z = logf(gw / aaw[j]);
                rv.w = logf(gh / aah[j]);
            }
            regv[j] = rv;
            keyv[j] = sortkey32(scv[j]);
            const u32 fl = pos ? 1u : (neg ? 2u : 0u);
            flagpack |= fl << (8 * j);
            if (fl) atomicAdd(&lh[keyv[j] >> 21], fl == 2u ? 0x10000u : 1u);
        }
        const size_t NK = (size_t)NI * KA;
        ((float4*)out)[nk >> 2] = make_float4(clsv[0], clsv[1], clsv[2], clsv[3]);
        float4* regp = ((float4*)(out + NK)) + nk;
        regp[0] = regv[0]; regp[1] = regv[1]; regp[2] = regv[2]; regp[3] = regv[3];
    }
    __syncthreads();
    {   // merge packed LDS histogram (device-scope atomics)
        const int gp = 2 * n;
        for (int i = tid; i < 2048; i += 256) {
            const u32 c = lh[i];
            if (c & 0xFFFFu) atomicAdd(&hist[gp * 2048 + i], c & 0xFFFFu);
            if (c >> 16)     atomicAdd(&hist[(gp + 1) * 2048 + i], c >> 16);
        }
    }
    gbar(&bars[0]);

    // ---------- P2: per-group boundary 11-bit bin (blocks 0..7) ----------
    if (bx < 8) {
        const int g = bx;
        u32 loc[8];
        u32 s = 0;
        const int base = g * 2048 + tid * 8;
        #pragma unroll
        for (int j = 0; j < 8; ++j) { loc[j] = aload(&hist[base + j]); s += loc[j]; }
        cs[tid] = s;
        __syncthreads();
        for (int d = 1; d < 256; d <<= 1) {
            const u32 add = (tid + d < 256) ? cs[tid + d] : 0u;
            __syncthreads();
            cs[tid] += add;
            __syncthreads();
        }
        if (tid == 0) astore(&meta[16 + g], (cs[0] < NSEL) ? 1u : 0u);
        u32 run = (tid < 255) ? cs[tid + 1] : 0u;
        #pragma unroll
        for (int j = 7; j >= 0; --j) {
            const u32 Sj = run + loc[j];
            if (Sj >= NSEL && run < NSEL) {
                astore(&meta[g], (u32)(tid * 8 + j));   // boundary 11-bit prefix
                astore(&meta[8 + g], NSEL - run);       // R1: slots within bin
            }
            run = Sj;
        }
    }
    gbar(&bars[1]);

    // ---------- P3: weights from registers + tie collection ----------
    if (tid < 32) s_meta[tid] = aload(&meta[tid]);
    __syncthreads();
    float cw[4], rw[4];
    u32 pslot[4] = {0xFFFFFFFFu, 0xFFFFFFFFu, 0xFFFFFFFFu, 0xFFFFFFFFu};
    u32 pgrp[4] = {0, 0, 0, 0};
    bool anydef = false;
    if (act) {
        #pragma unroll
        for (int j = 0; j < 4; ++j) {
            const u32 f = (flagpack >> (8 * j)) & 255u;
            bool in = false;
            if (f) {
                const int gi = (f == 2u) ? 1 : 0;
                const int g = 2 * n + gi;
                if (s_meta[16 + g]) {
                    in = true;                   // group < 256 members: take all
                } else {
                    const u32 p11 = keyv[j] >> 21;
                    if (p11 > s_meta[g]) {
                        in = true;
                    } else if (p11 == s_meta[g]) {
                        // boundary-bin member: defer verdict to P4/P5
                        const u32 p = atomicAdd(&meta[24 + g], 1u);
                        if (p < CAPL) {
                            astore(&list[(g * CAPL + p) * 2], keyv[j]);
                            astore(&list[(g * CAPL + p) * 2 + 1], (u32)(k0 + j));
                            pslot[j] = p;
                            pgrp[j] = (u32)g;
                            anydef = true;
                        }
                    }
                }
            }
            cw[j] = in ? 1.0f : 0.0f;
            rw[j] = (in && f == 1u) ? 1.0f : 0.0f;
        }
        if (!anydef) {   // single-writer lines: owners store; deferred wait for P5
            const size_t NK4 = (size_t)(NI * KA) / 4;
            const int t4 = (n * KA + k0) >> 2;
            ((float4*)out)[5 * NK4 + t4] = make_float4(cw[0], cw[1], cw[2], cw[3]);
            ((float4*)out)[6 * NK4 + t4] = make_float4(rw[0], rw[1], rw[2], rw[3]);
        }
    }
    gbar(&bars[2]);

    // ---------- P4: refine boundary bin -> verdict per slot (blocks 0..7) ----------
    if (bx < 8) {
        const int g = bx;
        if (!aload(&meta[16 + g])) {
            u32 c = aload(&meta[24 + g]);
            if (c > CAPL) c = CAPL;
            const u32 R1 = aload(&meta[8 + g]);
            for (u32 i = tid; i < 1024; i += 256) h2[i] = 0;
            if (tid == 0) s_tc = 0;
            __syncthreads();
            for (u32 j = tid; j < c; j += 256)
                atomicAdd(&h2[(aload(&list[(g * CAPL + j) * 2]) >> 11) & 1023u], 1u);
            __syncthreads();
            u32 loc[4];
            u32 s = 0;
            #pragma unroll
            for (int j = 0; j < 4; ++j) { loc[j] = h2[tid * 4 + j]; s += loc[j]; }
            cs[tid] = s;
            __syncthreads();
            for (int d = 1; d < 256; d <<= 1) {
                const u32 add = (tid + d < 256) ? cs[tid + d] : 0u;
                __syncthreads();
                cs[tid] += add;
                __syncthreads();
            }
            u32 run = (tid < 255) ? cs[tid + 1] : 0u;
            #pragma unroll
            for (int j = 3; j >= 0; --j) {
                const u32 Sj = run + loc[j];
                if (Sj >= R1 && run < R1) { s_usb = (u32)(tid * 4 + j); s_R2 = R1 - run; }
                run = Sj;
            }
            __syncthreads();
            const u32 usb = s_usb, R2 = s_R2;
            for (u32 j = tid; j < c; j += 256) {
                const u32 key = aload(&list[(g * CAPL + j) * 2]);
                const u32 sb = (key >> 11) & 1023u;
                if (sb > usb) {
                    astore(&verd[g * CAPL + j], 1u);
                } else if (sb < usb) {
                    astore(&verd[g * CAPL + j], 0u);
                } else {
                    const u32 p = atomicAdd(&s_tc, 1u);
                    if (p < 256) {
                        tk[p] = key;
                        ti[p] = aload(&list[(g * CAPL + j) * 2 + 1]);
                        tj[p] = j;
                    } else {
                        astore(&verd[g * CAPL + j], 0u);   // overflow: drop (can't happen)
                    }
                }
            }
            __syncthreads();
            u32 tc = s_tc;
            if (tc > 256) tc = 256;
            // rank tie set by (key desc, global idx asc) — stable top_k semantics
            for (u32 i = tid; i < tc; i += 256) {
                const u32 ki = tk[i], ii = ti[i];
                u32 rank = 0;
                for (u32 j2 = 0; j2 < tc; ++j2) {
                    const u32 kj = tk[j2];
                    if (kj > ki || (kj == ki && ti[j2] < ii)) rank++;
                }
                astore(&verd[g * CAPL + tj[i]], (rank < R2) ? 1u : 0u);
            }
        }
    }
    gbar(&bars[3]);

    // ---------- P5: deferred owners patch verdicts and store weights ----------
    if (act && anydef) {
        #pragma unroll
        for (int j = 0; j < 4; ++j) {
            if (pslot[j] != 0xFFFFFFFFu) {
                const u32 v = aload(&verd[pgrp[j] * CAPL + pslot[j]]);
                const u32 f = (flagpack >> (8 * j)) & 255u;
                cw[j] = v ? 1.0f : 0.0f;
                rw[j] = (v && f == 1u) ? 1.0f : 0.0f;
            }
        }
        const size_t NK4 = (size_t)(NI * KA) / 4;
        const int t4 = (n * KA + k0) >> 2;
        ((float4*)out)[5 * NK4 + t4] = make_float4(cw[0], cw[1], cw[2], cw[3]);
        ((float4*)out)[6 * NK4 + t4] = make_float4(rw[0], rw[1], rw[2], rw[3]);
    }
}

extern "C" void kernel_launch(void* const* d_in, const int* in_sizes, int n_in,
                              void* d_out, int out_size, void* d_ws, size_t ws_size,
                              hipStream_t stream) {
    (void)in_sizes; (void)n_in; (void)out_size; (void)ws_size;
    const float4* anchors = (const float4*)d_in[0];   // (K,4) f32
    const float*  scores  = (const float*)d_in[1];    // (N,K) f32
    const float4* gtb     = (const float4*)d_in[2];   // (N,M,4) f32
    const int*    glab    = (const int*)d_in[3];      // (N,M) int32
    float* out = (float*)d_out;
    u32* ws = (u32*)d_ws;

    kZ<<<32, 256, 0, stream>>>(ws);
    AnchorTargetLayer_48052094107725_kernel<<<GRID, 256, 0, stream>>>(
        anchors, scores, gtb, glab, out, ws);
}

// Round 17
// 137.124 us; speedup vs baseline: 6.0190x; 6.0190x over previous
//
#include <hip/hip_runtime.h>

// Problem constants (from reference)
#define KA 240000
#define NI 4
#define MG 50
#define NSEL 256u
#define CAPL 4096          // boundary-bin member cap per group (expect ~260)
#define BPI 235            // blocks per image: 235*256*4 = 240640 >= 240000
#define GRID (BPI * NI)    // 940 blocks

typedef unsigned int u32;

// ws layout (u32 units): hist 8x2048 @0 | meta[32] @16384 | list @16416 (8*CAPL*2)
// meta: us[0..8) | R[8..16) | done[16..24) | cnt[24..32)
#define METAO 16384
#define LISTO (METAO + 32)
#define ONE_F 0x3F800000u   // 1.0f bits

// monotone f32 -> u32 sortkey (order-preserving for all finite floats)
static __device__ __forceinline__ u32 sortkey32(float f) {
    u32 b = __float_as_uint(f);
    return (b & 0x80000000u) ? ~b : (b | 0x80000000u);
}
// agent-scope atomic dword store: bypasses per-XCD L2, so scattered 1.0 patches
// from blocks on different XCDs can share a 64B line without lost updates.
static __device__ __forceinline__ void patch1(u32* p) {
    __hip_atomic_store(p, ONE_F, __ATOMIC_RELAXED, __HIP_MEMORY_SCOPE_AGENT);
}

// ---------------- D1: fused zero + IoU/argmax + targets + weight-prewrite + hist ----------------
// Inputs are f32 (established R5-R13). Weight regions are pre-written 0.0 here
// (streaming float4, overlapped with the VALU-bound IoU loop); D2/D3 only patch
// the ~2k selected anchors to 1.0 via L2-bypassing atomic stores.
extern "C" __global__ void __launch_bounds__(256, 4)
AnchorTargetLayer_48052094107725_kernel(
    const float4* __restrict__ anchors, const float* __restrict__ scores,
    const float4* __restrict__ gtb, const int* __restrict__ glab,
    float* __restrict__ out, u32* __restrict__ flags, u32* __restrict__ ws) {
#pragma clang fp contract(off)
    __shared__ float4 gA[MG];
    __shared__ int glb[MG];
    __shared__ u32 lh[2048];        // packed hist: pos low16 | neg high16
    const int bx = blockIdx.x;
    const int tid = threadIdx.x;
    const int n = bx / BPI;
    const int kb = bx - n * BPI;

    if (tid < 18) {
        const int i = bx * 18 + tid;      // 940*18 = 16920 >= 16416
        if (i < LISTO) atomicExch(&ws[i], 0u);   // coherent with later atomicAdd merges
    }
    for (int i = tid; i < 2048; i += 256) lh[i] = 0;
    if (tid < MG) {
        gA[tid] = gtb[n * MG + tid];
        glb[tid] = glab[n * MG + tid];
    }
    __syncthreads();

    const int k0 = (kb * 256 + tid) * 4;   // 4 consecutive anchors (KA%4==0)
    if (k0 < KA) {
        float ax0[4], ay0[4], ax2[4], ay2[4];
        #pragma unroll
        for (int j = 0; j < 4; ++j) {
            const float4 A = anchors[k0 + j];
            ax0[j] = A.x; ay0[j] = A.y; ax2[j] = A.z; ay2[j] = A.w;
        }
        float aaw[4], aah[4], aar[4], bst[4];
        int bix[4];
        #pragma unroll
        for (int j = 0; j < 4; ++j) {
            aaw[j] = ax2[j] - ax0[j];
            aah[j] = ay2[j] - ay0[j];
            aar[j] = aaw[j] * aah[j];
            bst[j] = -1.0f;
            bix[j] = 0;
        }
        for (int m = 0; m < MG; m += 2) {
            const float4 Ga = gA[m];
            const float4 Gb = gA[m + 1];
            const float gaA = (Ga.z - Ga.x) * (Ga.w - Ga.y);   // same ops as reference
            const float gaB = (Gb.z - Gb.x) * (Gb.w - Gb.y);
            #pragma unroll
            for (int j = 0; j < 4; ++j) {
                const float wa = fmaxf(fminf(ax2[j], Ga.z) - fmaxf(ax0[j], Ga.x), 0.0f);
                const float ha = fmaxf(fminf(ay2[j], Ga.w) - fmaxf(ay0[j], Ga.y), 0.0f);
                const float ia = wa * ha;
                const float qa = ia / (((aar[j] + gaA) - ia) + 1e-8f);  // IEEE f32 div
                const float wb = fmaxf(fminf(ax2[j], Gb.z) - fmaxf(ax0[j], Gb.x), 0.0f);
                const float hb = fmaxf(fminf(ay2[j], Gb.w) - fmaxf(ay0[j], Gb.y), 0.0f);
                const float ib = wb * hb;
                const float qb = ib / (((aar[j] + gaB) - ib) + 1e-8f);
                if (qa > bst[j]) { bst[j] = qa; bix[j] = m; }       // strict >: first idx
                if (qb > bst[j]) { bst[j] = qb; bix[j] = m + 1; }
            }
        }

        const int nk = n * KA + k0;
        const float4 s4 = ((const float4*)scores)[nk >> 2];
        const float scv[4] = {s4.x, s4.y, s4.z, s4.w};

        float clsv[4];
        float4 regv[4];
        u32 flagpack = 0;
        #pragma unroll
        for (int j = 0; j < 4; ++j) {
            const bool pos = bst[j] >= 0.7f;
            const bool neg = bst[j] < 0.3f;
            clsv[j] = pos ? (float)glb[bix[j]] : 0.0f;
            float4 rv = make_float4(0.0f, 0.0f, 0.0f, 0.0f);
            if (pos) {
                const float4 Gm = gA[bix[j]];
                const float gw = Gm.z - Gm.x, gh = Gm.w - Gm.y;
                const float gcx = Gm.x + 0.5f * gw, gcy = Gm.y + 0.5f * gh;
                const float acx = ax0[j] + 0.5f * aaw[j], acy = ay0[j] + 0.5f * aah[j];
                rv.x = (gcx - acx) / aaw[j];
                rv.y = (gcy - acy) / aah[j];
                rv.z = logf(gw / aaw[j]);
                rv.w = logf(gh / aah[j]);
            }
            regv[j] = rv;
            const u32 fl = pos ? 1u : (neg ? 2u : 0u);
            flagpack |= fl << (8 * j);
            if (fl) atomicAdd(&lh[sortkey32(scv[j]) >> 21], fl == 2u ? 0x10000u : 1u);
        }
        const size_t NK = (size_t)NI * KA;
        const size_t NK4 = NK / 4;
        const int t4 = nk >> 2;
        ((float4*)out)[t4] = make_float4(clsv[0], clsv[1], clsv[2], clsv[3]);
        float4* regp = ((float4*)(out + NK)) + nk;
        regp[0] = regv[0]; regp[1] = regv[1]; regp[2] = regv[2]; regp[3] = regv[3];
        const float4 z4 = make_float4(0.0f, 0.0f, 0.0f, 0.0f);
        ((float4*)out)[5 * NK4 + t4] = z4;   // cls_weights prewrite
        ((float4*)out)[6 * NK4 + t4] = z4;   // reg_weights prewrite
        flags[t4] = flagpack;
    }
    __syncthreads();
    // merge packed LDS histogram into per-group global hist
    const int gp = 2 * n;
    for (int i = tid; i < 2048; i += 256) {
        const u32 c = lh[i];
        if (c & 0xFFFFu) atomicAdd(&ws[gp * 2048 + i], c & 0xFFFFu);
        if (c >> 16)     atomicAdd(&ws[(gp + 1) * 2048 + i], c >> 16);
    }
}

// ---------------- D2: boundary scan + sparse weight patches + tie collection ----------------
__global__ void __launch_bounds__(256) kP(const float* __restrict__ scores,
                                          const u32* __restrict__ flagsW,
                                          u32* __restrict__ ws,
                                          float* __restrict__ out) {
    __shared__ u32 cs[256];
    __shared__ u32 s_us[2], s_R[2], s_done[2];
    const int bx = blockIdx.x, tid = threadIdx.x;
    const int n = bx / BPI, kb = bx - n * BPI;
    u32* hist = ws;
    u32* meta = ws + METAO;
    u32* list = ws + LISTO;

    // boundary for both groups of this image (redundant per block; hist is L2-hot)
    for (int gi = 0; gi < 2; ++gi) {
        const int g = 2 * n + gi;
        u32 loc[8];
        u32 s = 0;
        const int base = g * 2048 + tid * 8;
        #pragma unroll
        for (int j = 0; j < 8; ++j) { loc[j] = hist[base + j]; s += loc[j]; }
        cs[tid] = s;
        __syncthreads();
        for (int d = 1; d < 256; d <<= 1) {
            const u32 add = (tid + d < 256) ? cs[tid + d] : 0u;
            __syncthreads();
            cs[tid] += add;
            __syncthreads();
        }
        if (tid == 0) s_done[gi] = (cs[0] < NSEL) ? 1u : 0u;
        u32 run = (tid < 255) ? cs[tid + 1] : 0u;
        #pragma unroll
        for (int j = 7; j >= 0; --j) {
            const u32 Sj = run + loc[j];
            if (Sj >= NSEL && run < NSEL) {
                s_us[gi] = (u32)(tid * 8 + j);   // boundary 11-bit prefix
                s_R[gi] = NSEL - run;            // slots within boundary bin
            }
            run = Sj;
        }
        __syncthreads();
    }
    if (kb == 0 && tid == 0) {                   // publish for D3 (one writer/image)
        meta[2 * n] = s_us[0];     meta[8 + 2 * n] = s_R[0];     meta[16 + 2 * n] = s_done[0];
        meta[2 * n + 1] = s_us[1]; meta[8 + 2 * n + 1] = s_R[1]; meta[16 + 2 * n + 1] = s_done[1];
    }

    const int k0 = (kb * 256 + tid) * 4;
    if (k0 >= KA) return;
    const int nk = n * KA + k0;
    const u32 fw = flagsW[nk >> 2];
    if (!fw) return;                             // no members among these 4 anchors
    const float4 s4 = ((const float4*)scores)[nk >> 2];
    const float scv[4] = {s4.x, s4.y, s4.z, s4.w};
    const size_t NK = (size_t)NI * KA;
    u32* o32 = (u32*)out;
    #pragma unroll
    for (int j = 0; j < 4; ++j) {
        const u32 f = (fw >> (8 * j)) & 255u;
        if (!f) continue;
        const int gi = (f == 2u) ? 1 : 0;
        bool in = false;
        if (s_done[gi]) {
            in = true;                            // group < 256 members: take all
        } else {
            const u32 key = sortkey32(scv[j]);
            const u32 p11 = key >> 21;
            if (p11 > s_us[gi]) {
                in = true;
            } else if (p11 == s_us[gi]) {
                // boundary-bin member: defer verdict to D3 (weight stays 0)
                const int g = 2 * n + gi;
                const u32 p = atomicAdd(&meta[24 + g], 1u);
                if (p < CAPL) {
                    list[(g * CAPL + p) * 2] = key;
                    list[(g * CAPL + p) * 2 + 1] = (u32)(k0 + j);
                }
            }
        }
        if (in) {
            patch1(&o32[5 * NK + nk + j]);                 // cls_weights = 1.0
            if (f == 1u) patch1(&o32[6 * NK + nk + j]);    // reg_weights = 1.0
        }
    }
}

// ---------------- D3: boundary-bin refinement + atomic fixups (8 blocks) ----------------
__global__ void __launch_bounds__(256) kR2(const u32* __restrict__ ws,
                                           float* __restrict__ out) {
    __shared__ u32 h2[1024];
    __shared__ u32 cs[256];
    __shared__ u32 s_usb, s_R2, s_tc;
    __shared__ u32 tk[256], ti[256];
    const u32* meta = ws + METAO;
    const u32* list = ws + LISTO;
    const int g = blockIdx.x, tid = threadIdx.x;
    if (meta[16 + g]) return;                 // take-all group (uniform return)
    u32 c = meta[24 + g];
    if (c > CAPL) c = CAPL;
    const u32 R1 = meta[8 + g];
    for (u32 i = tid; i < 1024; i += 256) h2[i] = 0;
    if (tid == 0) s_tc = 0;
    __syncthreads();
    for (u32 j = tid; j < c; j += 256)
        atomicAdd(&h2[(list[(g * CAPL + j) * 2] >> 11) & 1023u], 1u);
    __syncthreads();
    // suffix scan over 1024 sub-bins
    u32 loc[4];
    u32 s = 0;
    #pragma unroll
    for (int j = 0; j < 4; ++j) { loc[j] = h2[tid * 4 + j]; s += loc[j]; }
    cs[tid] = s;
    __syncthreads();
    for (int d = 1; d < 256; d <<= 1) {
        const u32 add = (tid + d < 256) ? cs[tid + d] : 0u;
        __syncthreads();
        cs[tid] += add;
        __syncthreads();
    }
    u32 run = (tid < 255) ? cs[tid + 1] : 0u;
    #pragma unroll
    for (int j = 3; j >= 0; --j) {
        const u32 Sj = run + loc[j];
        if (Sj >= R1 && run < R1) { s_usb = (u32)(tid * 4 + j); s_R2 = R1 - run; }
        run = Sj;
    }
    __syncthreads();
    const u32 usb = s_usb, R2 = s_R2;
    const int nn = g >> 1;
    const bool posg = ((g & 1) == 0);
    const size_t NK = (size_t)NI * KA;
    u32* o32 = (u32*)out;
    for (u32 j = tid; j < c; j += 256) {
        const u32 key = list[(g * CAPL + j) * 2];
        const u32 idx = list[(g * CAPL + j) * 2 + 1];
        const u32 sb = (key >> 11) & 1023u;
        if (sb > usb) {
            const size_t o = (size_t)nn * KA + idx;
            patch1(&o32[5 * NK + o]);
            if (posg) patch1(&o32[6 * NK + o]);
        } else if (sb == usb) {
            const u32 p = atomicAdd(&s_tc, 1u);
            if (p < 256) { tk[p] = key; ti[p] = idx; }
        }
    }
    __syncthreads();
    u32 tc = s_tc;
    if (tc > 256) tc = 256;
    // rank tiny tie set by (key desc, idx asc) — stable top_k semantics
    for (u32 i = tid; i < tc; i += 256) {
        const u32 ki = tk[i], ii = ti[i];
        u32 rank = 0;
        for (u32 j = 0; j < tc; ++j) {
            const u32 kj = tk[j];
            if (kj > ki || (kj == ki && ti[j] < ii)) rank++;
        }
        if (rank < R2) {
            const size_t o = (size_t)nn * KA + ii;
            patch1(&o32[5 * NK + o]);
            if (posg) patch1(&o32[6 * NK + o]);
        }
    }
}

extern "C" void kernel_launch(void* const* d_in, const int* in_sizes, int n_in,
                              void* d_out, int out_size, void* d_ws, size_t ws_size,
                              hipStream_t stream) {
    (void)in_sizes; (void)n_in; (void)out_size; (void)ws_size;
    const float4* anchors = (const float4*)d_in[0];   // (K,4) f32
    const float*  scores  = (const float*)d_in[1];    // (N,K) f32
    const float4* gtb     = (const float4*)d_in[2];   // (N,M,4) f32
    const int*    glab    = (const int*)d_in[3];      // (N,M) int32
    float* out = (float*)d_out;

    u32* ws = (u32*)d_ws;
    u32* flags = ws + LISTO + 8 * CAPL * 2;           // u32 per 4 anchors

    AnchorTargetLayer_48052094107725_kernel<<<GRID, 256, 0, stream>>>(
        anchors, scores, gtb, glab, out, flags, ws);
    kP<<<GRID, 256, 0, stream>>>(scores, flags, ws, out);
    kR2<<<8, 256, 0, stream>>>(ws, out);
}